// Round 1
// baseline (646.890 us; speedup 1.0000x reference)
//
#include <hip/hip_runtime.h>

#define NTHREADS 256

static __device__ __forceinline__ float clip10(float x) {
    return fminf(10.0f, fmaxf(-10.0f, x));
}

// Pass 1: histogram of exp(clip(lr)) into time buckets.
__global__ void cox_hist(const float* __restrict__ lr, const float* __restrict__ tm,
                         float* __restrict__ bucket, int n, int B) {
    int i = blockIdx.x * blockDim.x + threadIdx.x;
    int base = i * 4;
    if (base >= n) return;
    float fB = (float)B;
    if (base + 3 < n) {
        float4 l = ((const float4*)lr)[i];
        float4 t = ((const float4*)tm)[i];
        #pragma unroll
        for (int j = 0; j < 4; ++j) {
            float lv = ((const float*)&l)[j];
            float tv = ((const float*)&t)[j];
            float e = expf(clip10(lv));
            unsigned b = (unsigned)(tv * fB);
            if (b >= (unsigned)B) b = B - 1;
            unsafeAtomicAdd(&bucket[b], e);
        }
    } else {
        for (int k = base; k < n; ++k) {
            float e = expf(clip10(lr[k]));
            unsigned b = (unsigned)(tm[k] * fB);
            if (b >= (unsigned)B) b = B - 1;
            unsafeAtomicAdd(&bucket[b], e);
        }
    }
}

// Pass 2a: per-block (4096 buckets) sums.
__global__ void scan_blocksums(const float* __restrict__ cum, float* __restrict__ bs) {
    int t = threadIdx.x;
    size_t base = (size_t)blockIdx.x * 4096 + (size_t)t * 16;
    const float4* p = (const float4*)(cum + base);
    float s = 0.0f;
    #pragma unroll
    for (int j = 0; j < 4; ++j) {
        float4 v = p[j];
        s += v.x + v.y + v.z + v.w;
    }
    __shared__ float sh[NTHREADS];
    sh[t] = s; __syncthreads();
    for (int d = NTHREADS / 2; d > 0; d >>= 1) {
        if (t < d) sh[t] += sh[t + d];
        __syncthreads();
    }
    if (t == 0) bs[blockIdx.x] = sh[0];
}

// Pass 2b: suffix-exclusive offsets over block sums (single block).
__global__ void scan_offsets(const float* __restrict__ bs, float* __restrict__ off, int nb) {
    __shared__ float sh[1024];
    int t = threadIdx.x;
    float s = (t < nb) ? bs[t] : 0.0f;
    sh[t] = s;
    __syncthreads();
    for (int d = 1; d < 1024; d <<= 1) {
        float add = (t >= d) ? sh[t - d] : 0.0f;
        __syncthreads();
        sh[t] += add;
        __syncthreads();
    }
    float total = sh[1023];
    if (t < nb) off[t] = total - sh[t];  // sum of all block sums strictly after t
}

// Pass 2c: within-block suffix-inclusive scan + offset, in place.
__global__ void scan_final(float* __restrict__ cum, const float* __restrict__ off) {
    int t = threadIdx.x;
    size_t base = (size_t)blockIdx.x * 4096 + (size_t)t * 16;
    float4* p = (float4*)(cum + base);
    float v[16];
    float s = 0.0f;
    #pragma unroll
    for (int j = 0; j < 4; ++j) {
        float4 q = p[j];
        v[j * 4 + 0] = q.x; v[j * 4 + 1] = q.y; v[j * 4 + 2] = q.z; v[j * 4 + 3] = q.w;
        s += q.x + q.y + q.z + q.w;
    }
    __shared__ float sh[NTHREADS];
    sh[t] = s;
    __syncthreads();
    for (int d = 1; d < NTHREADS; d <<= 1) {
        float add = (t >= d) ? sh[t - d] : 0.0f;
        __syncthreads();
        sh[t] += add;
        __syncthreads();
    }
    float total = sh[NTHREADS - 1];
    float run = off[blockIdx.x] + (total - sh[t]);  // suffix-exclusive of this thread's segment
    #pragma unroll
    for (int j = 15; j >= 0; --j) { run += v[j]; v[j] = run; }
    #pragma unroll
    for (int j = 0; j < 4; ++j)
        p[j] = make_float4(v[j * 4], v[j * 4 + 1], v[j * 4 + 2], v[j * 4 + 3]);
}

// Pass 3: per-sample loss terms, block-reduced, atomically accumulated.
__global__ void cox_loss(const float* __restrict__ lr, const float* __restrict__ tm,
                         const int* __restrict__ cen, const float* __restrict__ cum,
                         double* __restrict__ total, int* __restrict__ cnt, int n, int B) {
    int i = blockIdx.x * blockDim.x + threadIdx.x;
    int base = i * 4;
    double acc = 0.0;
    int c = 0;
    float fB = (float)B;
    if (base < n) {
        if (base + 3 < n) {
            float4 l = ((const float4*)lr)[i];
            float4 t = ((const float4*)tm)[i];
            int4 cz = ((const int4*)cen)[i];
            #pragma unroll
            for (int j = 0; j < 4; ++j) {
                float lv = ((const float*)&l)[j];
                float tv = ((const float*)&t)[j];
                int cv = ((const int*)&cz)[j];
                if (cv == 1) {
                    unsigned b = (unsigned)(tv * fB);
                    if (b >= (unsigned)B) b = B - 1;
                    float risk = cum[b];
                    acc += (double)(clip10(lv) - logf(risk + 1e-15f));
                    c++;
                }
            }
        } else {
            for (int k = base; k < n; ++k) {
                if (cen[k] == 1) {
                    unsigned b = (unsigned)(tm[k] * fB);
                    if (b >= (unsigned)B) b = B - 1;
                    float risk = cum[b];
                    acc += (double)(clip10(lr[k]) - logf(risk + 1e-15f));
                    c++;
                }
            }
        }
    }
    __shared__ double shd[NTHREADS];
    __shared__ int shi[NTHREADS];
    int t = threadIdx.x;
    shd[t] = acc; shi[t] = c;
    __syncthreads();
    for (int d = NTHREADS / 2; d > 0; d >>= 1) {
        if (t < d) { shd[t] += shd[t + d]; shi[t] += shi[t + d]; }
        __syncthreads();
    }
    if (t == 0) {
        unsafeAtomicAdd(total, shd[0]);
        atomicAdd(cnt, shi[0]);
    }
}

__global__ void cox_final(const double* __restrict__ total, const int* __restrict__ cnt,
                          float* __restrict__ out) {
    int c = *cnt;
    if (c < 1) c = 1;
    out[0] = (float)(-(*total) / (double)c);
}

extern "C" void kernel_launch(void* const* d_in, const int* in_sizes, int n_in,
                              void* d_out, int out_size, void* d_ws, size_t ws_size,
                              hipStream_t stream) {
    const float* lr = (const float*)d_in[0];
    const float* tm = (const float*)d_in[1];
    const int*   cen = (const int*)d_in[2];
    float* out = (float*)d_out;
    int n = in_sizes[0];

    // Choose bucket count B = 2^bbits to fit workspace (cap 2^22, floor 2^14).
    int bbits = 22;
    while (bbits > 14) {
        size_t B = (size_t)1 << bbits;
        size_t nb = B >> 12;
        if (4 * B + 8 * nb + 64 <= ws_size) break;
        bbits--;
    }
    int B = 1 << bbits;
    int NB = B >> 12;  // blocks of 4096 buckets each

    float* cum = (float*)d_ws;
    float* bs  = cum + B;
    float* off = bs + NB;
    double* total = (double*)(off + NB);  // 4B + 8NB bytes -> 8-aligned
    int* cnt = (int*)(total + 1);

    size_t zbytes = 4 * (size_t)B + 8 * (size_t)NB + 16;
    hipMemsetAsync(d_ws, 0, zbytes, stream);

    int n4v = (n + 3) / 4;
    int blocks = (n4v + NTHREADS - 1) / NTHREADS;
    cox_hist<<<blocks, NTHREADS, 0, stream>>>(lr, tm, cum, n, B);
    scan_blocksums<<<NB, NTHREADS, 0, stream>>>(cum, bs);
    scan_offsets<<<1, 1024, 0, stream>>>(bs, off, NB);
    scan_final<<<NB, NTHREADS, 0, stream>>>(cum, off);
    cox_loss<<<blocks, NTHREADS, 0, stream>>>(lr, tm, cen, cum, total, cnt, n, B);
    cox_final<<<1, 1, 0, stream>>>(total, cnt, out);
}

// Round 2
// 321.967 us; speedup vs baseline: 2.0092x; 2.0092x over previous
//
#include <hip/hip_runtime.h>

#define NTHREADS 256
#define B_BITS 12
#define NBUCK (1 << B_BITS)   // 4096 time buckets, 16 KB LDS per block
#define MAX_NBLK 1024

static __device__ __forceinline__ float clip10(float x) {
    return fminf(10.0f, fmaxf(-10.0f, x));
}

// Pass 1: per-block private LDS histogram of exp(clip(lr)) over time buckets,
// flushed to a per-block global slice. No global atomics.
__global__ void cox_hist(const float* __restrict__ lr, const float* __restrict__ tm,
                         float* __restrict__ hist, int n) {
    __shared__ float h[NBUCK];
    for (int i = threadIdx.x; i < NBUCK; i += NTHREADS) h[i] = 0.0f;
    __syncthreads();

    const int n4 = n >> 2;
    const float fB = (float)NBUCK;
    const int stride = gridDim.x * NTHREADS;
    for (int i = blockIdx.x * NTHREADS + threadIdx.x; i < n4; i += stride) {
        float4 l = ((const float4*)lr)[i];
        float4 t = ((const float4*)tm)[i];
        #pragma unroll
        for (int j = 0; j < 4; ++j) {
            float lv = ((const float*)&l)[j];
            float tv = ((const float*)&t)[j];
            float e = expf(clip10(lv));
            unsigned b = (unsigned)(tv * fB);
            if (b >= NBUCK) b = NBUCK - 1;
            atomicAdd(&h[b], e);
        }
    }
    // Tail (n not divisible by 4) handled by block 0, thread 0.
    if (blockIdx.x == 0 && threadIdx.x == 0) {
        for (int k = n4 << 2; k < n; ++k) {
            float e = expf(clip10(lr[k]));
            unsigned b = (unsigned)(tm[k] * fB);
            if (b >= NBUCK) b = NBUCK - 1;
            atomicAdd(&h[b], e);
        }
    }
    __syncthreads();

    float* out = hist + (size_t)blockIdx.x * NBUCK;
    for (int i = threadIdx.x; i < NBUCK; i += NTHREADS) out[i] = h[i];
}

// Pass 2a: column reduce over the nblk private histograms.
// Each block owns 64 buckets; 4 k-partitions per bucket reduced via LDS.
__global__ void cox_reduce(const float* __restrict__ hist, float* __restrict__ bucket,
                           int nblk) {
    int t = threadIdx.x;
    int bb = (blockIdx.x << 6) + (t & 63);   // bucket index
    int kp = t >> 6;                         // k-partition 0..3
    float s = 0.0f;
    for (int k = kp; k < nblk; k += 4)
        s += hist[(size_t)k * NBUCK + bb];
    __shared__ float sh[NTHREADS];
    sh[t] = s;
    __syncthreads();
    if (t < 64)
        bucket[bb] = sh[t] + sh[t + 64] + sh[t + 128] + sh[t + 192];
}

// Pass 2b: single-block suffix-inclusive scan of the 4096 buckets, in place.
__global__ void cox_scan(float* __restrict__ bucket) {
    int t = threadIdx.x;
    float4* p = (float4*)(bucket + t * 16);
    float v[16];
    float s = 0.0f;
    #pragma unroll
    for (int j = 0; j < 4; ++j) {
        float4 q = p[j];
        v[j * 4 + 0] = q.x; v[j * 4 + 1] = q.y; v[j * 4 + 2] = q.z; v[j * 4 + 3] = q.w;
        s += q.x + q.y + q.z + q.w;
    }
    __shared__ float sh[NTHREADS];
    sh[t] = s;
    __syncthreads();
    for (int d = 1; d < NTHREADS; d <<= 1) {
        float add = (t >= d) ? sh[t - d] : 0.0f;
        __syncthreads();
        sh[t] += add;
        __syncthreads();
    }
    float total = sh[NTHREADS - 1];
    float run = total - sh[t];  // sum over threads strictly after t
    #pragma unroll
    for (int j = 15; j >= 0; --j) { run += v[j]; v[j] = run; }
    #pragma unroll
    for (int j = 0; j < 4; ++j)
        p[j] = make_float4(v[j * 4], v[j * 4 + 1], v[j * 4 + 2], v[j * 4 + 3]);
}

// Pass 3: per-sample loss terms, block-reduced, atomically accumulated.
__global__ void cox_loss(const float* __restrict__ lr, const float* __restrict__ tm,
                         const int* __restrict__ cen, const float* __restrict__ cum,
                         double* __restrict__ total, int* __restrict__ cnt, int n) {
    int i = blockIdx.x * NTHREADS + threadIdx.x;
    int base = i * 4;
    double acc = 0.0;
    int c = 0;
    const float fB = (float)NBUCK;
    if (base < n) {
        if (base + 3 < n) {
            float4 l = ((const float4*)lr)[i];
            float4 t = ((const float4*)tm)[i];
            int4 cz = ((const int4*)cen)[i];
            #pragma unroll
            for (int j = 0; j < 4; ++j) {
                float lv = ((const float*)&l)[j];
                float tv = ((const float*)&t)[j];
                int cv = ((const int*)&cz)[j];
                if (cv == 1) {
                    unsigned b = (unsigned)(tv * fB);
                    if (b >= NBUCK) b = NBUCK - 1;
                    acc += (double)(clip10(lv) - logf(cum[b] + 1e-15f));
                    c++;
                }
            }
        } else {
            for (int k = base; k < n; ++k) {
                if (cen[k] == 1) {
                    unsigned b = (unsigned)(tm[k] * fB);
                    if (b >= NBUCK) b = NBUCK - 1;
                    acc += (double)(clip10(lr[k]) - logf(cum[b] + 1e-15f));
                    c++;
                }
            }
        }
    }
    __shared__ double shd[NTHREADS];
    __shared__ int shi[NTHREADS];
    int t = threadIdx.x;
    shd[t] = acc; shi[t] = c;
    __syncthreads();
    for (int d = NTHREADS / 2; d > 0; d >>= 1) {
        if (t < d) { shd[t] += shd[t + d]; shi[t] += shi[t + d]; }
        __syncthreads();
    }
    if (t == 0) {
        unsafeAtomicAdd(total, shd[0]);
        atomicAdd(cnt, shi[0]);
    }
}

__global__ void cox_final(const double* __restrict__ total, const int* __restrict__ cnt,
                          float* __restrict__ out) {
    int c = *cnt;
    if (c < 1) c = 1;
    out[0] = (float)(-(*total) / (double)c);
}

extern "C" void kernel_launch(void* const* d_in, const int* in_sizes, int n_in,
                              void* d_out, int out_size, void* d_ws, size_t ws_size,
                              hipStream_t stream) {
    const float* lr  = (const float*)d_in[0];
    const float* tm  = (const float*)d_in[1];
    const int*   cen = (const int*)d_in[2];
    float* out = (float*)d_out;
    int n = in_sizes[0];

    // Workspace: nblk private histograms + bucket array + accumulators.
    size_t avail = (ws_size - (size_t)NBUCK * 4 - 64) / ((size_t)NBUCK * 4);
    int nblk = (int)(avail < MAX_NBLK ? avail : MAX_NBLK);
    if (nblk < 1) nblk = 1;

    float* hist   = (float*)d_ws;
    float* bucket = hist + (size_t)nblk * NBUCK;
    double* total = (double*)(bucket + NBUCK);
    int* cnt = (int*)(total + 1);

    hipMemsetAsync(total, 0, 16, stream);

    cox_hist<<<nblk, NTHREADS, 0, stream>>>(lr, tm, hist, n);
    cox_reduce<<<NBUCK / 64, NTHREADS, 0, stream>>>(hist, bucket, nblk);
    cox_scan<<<1, NTHREADS, 0, stream>>>(bucket);
    int n4v = (n + 3) / 4;
    int blocks = (n4v + NTHREADS - 1) / NTHREADS;
    cox_loss<<<blocks, NTHREADS, 0, stream>>>(lr, tm, cen, bucket, total, cnt, n);
    cox_final<<<1, 1, 0, stream>>>(total, cnt, out);
}

// Round 3
// 147.053 us; speedup vs baseline: 4.3990x; 2.1895x over previous
//
#include <hip/hip_runtime.h>

#define NTHREADS 256
#define NBUCK 4096
#define NCOL (2 * NBUCK)      // exp-hist | cnt-hist, per block slice
#define MAX_NBLK 1024

static __device__ __forceinline__ float clip10(float x) {
    return fminf(10.0f, fmaxf(-10.0f, x));
}

// Pass 1: ONE streaming pass over (lr, tm, cen).
// Per-block LDS histograms over 4096 time buckets:
//   he[b] += exp(clip(lr)),  hc[b] += (censor==1)
// plus block-level sum of clip(lr) over events (one double atomic per block).
// Each block flushes its private histograms to a global slice (no global
// per-bucket atomics).
__global__ void cox_pass1(const float* __restrict__ lr, const float* __restrict__ tm,
                          const int* __restrict__ cen, float* __restrict__ hist,
                          double* __restrict__ sum_lr, int n) {
    __shared__ float he[NBUCK];
    __shared__ float hc[NBUCK];
    for (int i = threadIdx.x; i < NBUCK; i += NTHREADS) { he[i] = 0.0f; hc[i] = 0.0f; }
    __syncthreads();

    const int n4 = n >> 2;
    const float fB = (float)NBUCK;
    const int stride = gridDim.x * NTHREADS;
    float lsum = 0.0f;
    for (int i = blockIdx.x * NTHREADS + threadIdx.x; i < n4; i += stride) {
        float4 l = ((const float4*)lr)[i];
        float4 t = ((const float4*)tm)[i];
        int4  cz = ((const int4*)cen)[i];
        #pragma unroll
        for (int j = 0; j < 4; ++j) {
            float lv = clip10(((const float*)&l)[j]);
            float tv = ((const float*)&t)[j];
            int   cv = ((const int*)&cz)[j];
            unsigned b = (unsigned)(tv * fB);
            if (b >= NBUCK) b = NBUCK - 1;
            atomicAdd(&he[b], expf(lv));
            if (cv == 1) { atomicAdd(&hc[b], 1.0f); lsum += lv; }
        }
    }
    // Tail (n not divisible by 4): block 0, thread 0.
    if (blockIdx.x == 0 && threadIdx.x == 0) {
        for (int k = n4 << 2; k < n; ++k) {
            float lv = clip10(lr[k]);
            unsigned b = (unsigned)(tm[k] * fB);
            if (b >= NBUCK) b = NBUCK - 1;
            atomicAdd(&he[b], expf(lv));
            if (cen[k] == 1) { atomicAdd(&hc[b], 1.0f); lsum += lv; }
        }
    }
    __syncthreads();

    // Flush private histograms (vectorized, coalesced).
    float* oe = hist + (size_t)blockIdx.x * NCOL;
    float* oc = oe + NBUCK;
    for (int i = threadIdx.x * 4; i < NBUCK; i += NTHREADS * 4) {
        *(float4*)(oe + i) = *(const float4*)(he + i);
        *(float4*)(oc + i) = *(const float4*)(hc + i);
    }

    // Block-reduce lsum, one double atomic per block.
    __shared__ double sd[NTHREADS];
    sd[threadIdx.x] = (double)lsum;
    __syncthreads();
    for (int d = NTHREADS / 2; d > 0; d >>= 1) {
        if (threadIdx.x < d) sd[threadIdx.x] += sd[threadIdx.x + d];
        __syncthreads();
    }
    if (threadIdx.x == 0) unsafeAtomicAdd(sum_lr, sd[0]);
}

// Pass 2: column reduce over the nblk private slices (8192 columns).
__global__ void cox_reduce(const float* __restrict__ hist, float* __restrict__ bucket,
                           int nblk) {
    int t = threadIdx.x;
    int col = (blockIdx.x << 6) + (t & 63);
    int kp = t >> 6;
    float s = 0.0f;
    for (int k = kp; k < nblk; k += 4)
        s += hist[(size_t)k * NCOL + col];
    __shared__ float sh[NTHREADS];
    sh[t] = s;
    __syncthreads();
    if (t < 64)
        bucket[(blockIdx.x << 6) + t] = sh[t] + sh[t + 64] + sh[t + 128] + sh[t + 192];
}

// Pass 3: single block. Suffix-inclusive scan of exp-buckets, then
// dot = sum_b cnt_b * log(cum_b + 1e-15), cnt = sum_b cnt_b, and final loss.
__global__ void cox_scanfinal(const float* __restrict__ bucket,
                              const double* __restrict__ sum_lr,
                              float* __restrict__ out) {
    int t = threadIdx.x;
    const float4* pe = (const float4*)(bucket + t * 16);
    const float4* pc = (const float4*)(bucket + NBUCK + t * 16);
    float v[16], c[16];
    float s = 0.0f;
    #pragma unroll
    for (int j = 0; j < 4; ++j) {
        float4 q = pe[j];
        v[j * 4 + 0] = q.x; v[j * 4 + 1] = q.y; v[j * 4 + 2] = q.z; v[j * 4 + 3] = q.w;
        s += q.x + q.y + q.z + q.w;
        float4 r = pc[j];
        c[j * 4 + 0] = r.x; c[j * 4 + 1] = r.y; c[j * 4 + 2] = r.z; c[j * 4 + 3] = r.w;
    }
    __shared__ float sh[NTHREADS];
    sh[t] = s;
    __syncthreads();
    for (int d = 1; d < NTHREADS; d <<= 1) {
        float add = (t >= d) ? sh[t - d] : 0.0f;
        __syncthreads();
        sh[t] += add;
        __syncthreads();
    }
    float total = sh[NTHREADS - 1];
    float run = total - sh[t];          // sum over threads strictly after t
    double dot = 0.0;
    float cs = 0.0f;
    #pragma unroll
    for (int j = 15; j >= 0; --j) {
        run += v[j];                    // suffix-inclusive cum at bucket t*16+j
        dot += (double)(c[j] * logf(run + 1e-15f));
        cs  += c[j];
    }
    __shared__ double sdd[NTHREADS];
    __shared__ float scc[NTHREADS];
    sdd[t] = dot; scc[t] = cs;
    __syncthreads();
    for (int d = NTHREADS / 2; d > 0; d >>= 1) {
        if (t < d) { sdd[t] += sdd[t + d]; scc[t] += scc[t + d]; }
        __syncthreads();
    }
    if (t == 0) {
        double tot = *sum_lr - sdd[0];
        float cnt = scc[0];
        double denom = (cnt < 1.0f) ? 1.0 : (double)cnt;
        out[0] = (float)(-tot / denom);
    }
}

extern "C" void kernel_launch(void* const* d_in, const int* in_sizes, int n_in,
                              void* d_out, int out_size, void* d_ws, size_t ws_size,
                              hipStream_t stream) {
    const float* lr  = (const float*)d_in[0];
    const float* tm  = (const float*)d_in[1];
    const int*   cen = (const int*)d_in[2];
    float* out = (float*)d_out;
    int n = in_sizes[0];

    // Workspace: nblk slices of (exp|cnt) + reduced buckets + sum_lr.
    size_t slice_bytes = (size_t)NCOL * 4;
    size_t fixed = slice_bytes + 64;                    // bucket array + accum
    size_t avail = (ws_size > fixed) ? (ws_size - fixed) / slice_bytes : 1;
    int nblk = (int)(avail < MAX_NBLK ? avail : MAX_NBLK);
    if (nblk < 1) nblk = 1;

    float* hist   = (float*)d_ws;
    float* bucket = hist + (size_t)nblk * NCOL;
    double* sum_lr = (double*)(bucket + NCOL);

    hipMemsetAsync(sum_lr, 0, 8, stream);

    cox_pass1<<<nblk, NTHREADS, 0, stream>>>(lr, tm, cen, hist, sum_lr, n);
    cox_reduce<<<NCOL / 64, NTHREADS, 0, stream>>>(hist, bucket, nblk);
    cox_scanfinal<<<1, NTHREADS, 0, stream>>>(bucket, sum_lr, out);
}